// Round 1
// baseline (135.155 us; speedup 1.0000x reference)
//
#include <hip/hip_runtime.h>
#include <hip/hip_bf16.h>

// Problem constants
#define BATCH   4096
#define NF      128    // n features == n models
#define NA      16
#define IN_DIM  144    // NF/... no: N_FEATURES + N_ACTIONS
#define KPAD    160    // IN_DIM padded to multiple of 32
#define HID     256

typedef __attribute__((ext_vector_type(8))) short bf16x8;
typedef __attribute__((ext_vector_type(4))) float f32x4;

// ---------------------------------------------------------------------------
// Kernel 1: fa = concat(f_t, a_t) -> bf16, padded to KPAD with zeros.
// Each thread writes one 16B chunk (8 bf16). 20 chunks per row (160 k).
// Chunk boundaries (multiples of 8) never straddle 128 or 144.
__global__ void convert_fa(const float* __restrict__ f_t,
                           const float* __restrict__ a_t,
                           __hip_bfloat16* __restrict__ fab) {
    int c = blockIdx.x * blockDim.x + threadIdx.x;
    const int total = BATCH * (KPAD / 8);
    if (c >= total) return;
    int row = c / 20;
    int k0 = (c - row * 20) * 8;
    union { ushort us[8]; uint4 q; } pk;
#pragma unroll
    for (int j = 0; j < 8; ++j) {
        int k = k0 + j;
        float v;
        if (k < NF)           v = f_t[(size_t)row * NF + k];
        else if (k < IN_DIM)  v = a_t[(size_t)row * NA + (k - NF)];
        else                  v = 0.0f;
        __hip_bfloat16 h = __float2bfloat16(v);
        pk.us[j] = *(ushort*)&h;
    }
    *(uint4*)(fab + (size_t)row * KPAD + k0) = pk.q;
}

// ---------------------------------------------------------------------------
// Kernel 2: W1 [128][144][256] fp32 -> W1T [128][256][160] bf16 (transposed,
// K zero-padded). LDS transpose: block handles (m, 16-k chunk), 256 threads.
__global__ void convert_w1t(const float* __restrict__ W1,
                            __hip_bfloat16* __restrict__ w1t) {
    __shared__ float tile[16][HID];
    int bid = blockIdx.x;
    int m = bid / 10;
    int kc = bid - m * 10;
    int t = threadIdx.x;       // 0..255 == output column
    int k0 = kc * 16;
    if (kc < 9) {
#pragma unroll
        for (int i = 0; i < 16; ++i) {
            tile[i][t] = W1[((size_t)m * IN_DIM + (k0 + i)) * HID + t];
        }
        __syncthreads();
        union { ushort us[16]; uint4 q[2]; } pk;
#pragma unroll
        for (int i = 0; i < 16; ++i) {
            __hip_bfloat16 h = __float2bfloat16(tile[i][t]);
            pk.us[i] = *(ushort*)&h;
        }
        uint4* dst = (uint4*)(w1t + ((size_t)m * HID + t) * KPAD + k0);
        dst[0] = pk.q[0];
        dst[1] = pk.q[1];
    } else {
        // pad region k = 144..159 -> zeros
        uint4 z = {0u, 0u, 0u, 0u};
        uint4* dst = (uint4*)(w1t + ((size_t)m * HID + t) * KPAD + IN_DIM);
        dst[0] = z;
        dst[1] = z;
    }
}

// ---------------------------------------------------------------------------
// Kernel 3: fused grouped GEMM + ReLU + W2 reduce + bias + skip.
// Block: 256 threads (4 waves). Tile: one model m, 64 batch rows, all 256 hid.
// Wave w owns hidden cols [w*64, w*64+64).
#define BT    64
#define ASTR  168   // As row stride in bf16 (160 + 8 pad -> 2-way banks)
#define BSTR  40    // Bs col stride in bf16 (32 + 8 pad -> 2-way banks)

__global__ __launch_bounds__(256) void gemm_fused(
        const __hip_bfloat16* __restrict__ fab,
        const __hip_bfloat16* __restrict__ w1t,
        const float* __restrict__ b1,
        const float* __restrict__ W2,
        const float* __restrict__ b2,
        const float* __restrict__ f_t,
        float* __restrict__ out) {
    __shared__ __hip_bfloat16 As[BT * ASTR];      // 21504 B
    __shared__ __hip_bfloat16 Bs[HID * BSTR];     // 20480 B
    __shared__ float partial[4][BT];              // 1024 B

    const int bid = blockIdx.x;
    const int m  = bid >> 6;        // 0..127  (consecutive blocks share m)
    const int bt = bid & 63;        // 0..63 batch tile
    const int t = threadIdx.x;
    const int w = t >> 6;           // wave 0..3
    const int lane = t & 63;
    const int lrow = lane & 15;
    const int lk8 = (lane >> 4) * 8;
    const int b0 = bt * BT;

    // ---- stage A: 64 rows x 160 k of fa -> As. 1280 x 16B chunks.
    for (int c = t; c < BT * 20; c += 256) {
        int row = c / 20;
        int ko = (c - row * 20) * 8;
        uint4 v = *(const uint4*)(fab + (size_t)(b0 + row) * KPAD + ko);
        *(uint4*)(&As[row * ASTR + ko]) = v;
    }

    f32x4 acc[4][4];
#pragma unroll
    for (int i = 0; i < 4; ++i)
#pragma unroll
        for (int j = 0; j < 4; ++j)
            acc[i][j] = (f32x4){0.f, 0.f, 0.f, 0.f};

    for (int ks = 0; ks < 5; ++ks) {
        __syncthreads();   // previous iter's Bs reads complete before overwrite
        // ---- stage B chunk: W1T[m][0..255][ks*32 .. +32] -> Bs. 1024 x 16B.
        for (int c = t; c < 1024; c += 256) {
            int col = c >> 2;
            int ko = (c & 3) * 8;
            uint4 v = *(const uint4*)(w1t + ((size_t)m * HID + col) * KPAD + ks * 32 + ko);
            *(uint4*)(&Bs[col * BSTR + ko]) = v;
        }
        __syncthreads();

        bf16x8 a[4], b[4];
#pragma unroll
        for (int mi = 0; mi < 4; ++mi)
            a[mi] = *(const bf16x8*)(&As[(mi * 16 + lrow) * ASTR + ks * 32 + lk8]);
#pragma unroll
        for (int ni = 0; ni < 4; ++ni)
            b[ni] = *(const bf16x8*)(&Bs[(w * 64 + ni * 16 + lrow) * BSTR + lk8]);
#pragma unroll
        for (int mi = 0; mi < 4; ++mi)
#pragma unroll
            for (int ni = 0; ni < 4; ++ni)
                acc[mi][ni] = __builtin_amdgcn_mfma_f32_16x16x32_bf16(
                    a[mi], b[ni], acc[mi][ni], 0, 0, 0);
    }

    // ---- epilogue: relu(acc + b1) * W2, reduce over hidden.
    // C frag layout (verified m89): col = lane&15, row = (lane>>4)*4 + reg.
    float w2v[4], b1v[4];
#pragma unroll
    for (int ni = 0; ni < 4; ++ni) {
        int col = w * 64 + ni * 16 + lrow;
        w2v[ni] = W2[(size_t)m * HID + col];
        b1v[ni] = b1[(size_t)m * HID + col];
    }
    const int g = lane >> 4;
#pragma unroll
    for (int mi = 0; mi < 4; ++mi) {
        float s[4] = {0.f, 0.f, 0.f, 0.f};
#pragma unroll
        for (int ni = 0; ni < 4; ++ni)
#pragma unroll
            for (int r = 0; r < 4; ++r) {
                float h = acc[mi][ni][r] + b1v[ni];
                h = h > 0.f ? h : 0.f;
                s[r] += h * w2v[ni];
            }
        // reduce over the 16 cols held by lanes (lane&15)
#pragma unroll
        for (int r = 0; r < 4; ++r) {
            for (int off = 1; off < 16; off <<= 1)
                s[r] += __shfl_xor(s[r], off, 64);
        }
        if (lrow == 0) {
#pragma unroll
            for (int r = 0; r < 4; ++r)
                partial[w][mi * 16 + g * 4 + r] = s[r];
        }
    }
    __syncthreads();
    if (t < BT) {
        int row = b0 + t;
        float v = partial[0][t] + partial[1][t] + partial[2][t] + partial[3][t]
                + b2[m] + f_t[(size_t)row * NF + m];
        out[(size_t)row * NF + m] = v;
    }
}

// ---------------------------------------------------------------------------
extern "C" void kernel_launch(void* const* d_in, const int* in_sizes, int n_in,
                              void* d_out, int out_size, void* d_ws, size_t ws_size,
                              hipStream_t stream) {
    const float* f_t = (const float*)d_in[0];
    const float* a_t = (const float*)d_in[1];
    const float* W1  = (const float*)d_in[2];
    const float* b1  = (const float*)d_in[3];
    const float* W2  = (const float*)d_in[4];
    const float* b2  = (const float*)d_in[5];
    float* out = (float*)d_out;

    // ws layout: W1T bf16 [128][256][160] then fa bf16 [4096][160]
    __hip_bfloat16* w1t = (__hip_bfloat16*)d_ws;
    __hip_bfloat16* fab = (__hip_bfloat16*)((char*)d_ws + (size_t)NF * HID * KPAD * 2);

    hipLaunchKernelGGL(convert_w1t, dim3(NF * 10), dim3(256), 0, stream, W1, w1t);
    hipLaunchKernelGGL(convert_fa, dim3((BATCH * (KPAD / 8) + 255) / 256), dim3(256), 0, stream,
                       f_t, a_t, fab);
    hipLaunchKernelGGL(gemm_fused, dim3(NF * (BATCH / BT)), dim3(256), 0, stream,
                       fab, w1t, b1, W2, b2, f_t, out);
}

// Round 2
// 97.123 us; speedup vs baseline: 1.3916x; 1.3916x over previous
//
#include <hip/hip_runtime.h>
#include <hip/hip_bf16.h>

// Problem constants
#define BATCH   4096
#define NF      128    // n features == n models
#define NA      16
#define IN_DIM  144    // N_FEATURES + N_ACTIONS
#define KPAD    160    // IN_DIM padded to multiple of 32
#define HID     256

typedef __attribute__((ext_vector_type(8))) short bf16x8;
typedef __attribute__((ext_vector_type(4))) float f32x4;

// ---------------------------------------------------------------------------
// Kernel 1: fa = concat(f_t, a_t) -> bf16, padded to KPAD with zeros.
// Each thread writes one 16B chunk (8 bf16). 20 chunks per row (160 k).
__global__ void convert_fa(const float* __restrict__ f_t,
                           const float* __restrict__ a_t,
                           __hip_bfloat16* __restrict__ fab) {
    int c = blockIdx.x * blockDim.x + threadIdx.x;
    const int total = BATCH * (KPAD / 8);
    if (c >= total) return;
    int row = c / 20;
    int k0 = (c - row * 20) * 8;
    union { ushort us[8]; uint4 q; } pk;
#pragma unroll
    for (int j = 0; j < 8; ++j) {
        int k = k0 + j;
        float v;
        if (k < NF)           v = f_t[(size_t)row * NF + k];
        else if (k < IN_DIM)  v = a_t[(size_t)row * NA + (k - NF)];
        else                  v = 0.0f;
        __hip_bfloat16 h = __float2bfloat16(v);
        pk.us[j] = *(ushort*)&h;
    }
    *(uint4*)(fab + (size_t)row * KPAD + k0) = pk.q;
}

// ---------------------------------------------------------------------------
// Kernel 2: fully-fused grouped MLP.
// Grid 256: block b -> model m = b>>1, batch half = (b&1)*2048.
// 512 threads = 8 waves: wr = w>>2 (row group), wc = w&3 (64-col group).
// B-operand (W1[m], fp32->bf16) lives ENTIRELY in registers (80 VGPR/wave),
// loaded once. A-frags stream from L2-resident bf16 fab. No operand LDS.
// Per iteration: 128-row x 256-hid tile, 5 K-steps, 80 MFMA/wave, 1 barrier.
__global__ __launch_bounds__(512, 2) void fused_mlp(
        const __hip_bfloat16* __restrict__ fab,
        const float* __restrict__ W1,
        const float* __restrict__ b1,
        const float* __restrict__ W2,
        const float* __restrict__ b2,
        const float* __restrict__ f_t,
        float* __restrict__ out) {
    __shared__ float partial[2][4][128];   // [dbuf][wc][row] = 4 KB

    const int bid = blockIdx.x;
    const int m  = bid >> 1;
    const int b0 = (bid & 1) * 2048;
    const int t = threadIdx.x;
    const int w = t >> 6;
    const int lane = t & 63;
    const int wr = w >> 2;          // 0..1
    const int wc = w & 3;           // 0..3
    const int lrow = lane & 15;
    const int g = lane >> 4;        // 0..3

    // ---- prologue: W1[m] -> register B-frags (bf16), b1/W2 per-lane, b2.
    // B-frag lane layout: col = lane&15 (+offsets), k = (lane>>4)*8 + j.
    bf16x8 bfrag[4][5];
#pragma unroll
    for (int ni = 0; ni < 4; ++ni) {
        const int col = wc * 64 + ni * 16 + lrow;
#pragma unroll
        for (int ks = 0; ks < 5; ++ks) {
            union { ushort us[8]; bf16x8 v; } pk;
#pragma unroll
            for (int j = 0; j < 8; ++j) {
                int k = ks * 32 + g * 8 + j;
                float v = (k < IN_DIM)
                        ? W1[((size_t)m * IN_DIM + k) * HID + col] : 0.0f;
                __hip_bfloat16 h = __float2bfloat16(v);
                pk.us[j] = *(ushort*)&h;
            }
            bfrag[ni][ks] = pk.v;
        }
    }
    float w2v[4], b1v[4];
#pragma unroll
    for (int ni = 0; ni < 4; ++ni) {
        int col = wc * 64 + ni * 16 + lrow;
        w2v[ni] = W2[(size_t)m * HID + col];
        b1v[ni] = b1[(size_t)m * HID + col];
    }
    const float b2v = b2[m];

    // ---- main loop: 16 tiles of 128 batch rows.
    for (int tile = 0; tile < 16; ++tile) {
        const int r0 = b0 + tile * 128 + wr * 64;

        f32x4 acc[4][4];
#pragma unroll
        for (int mi = 0; mi < 4; ++mi)
#pragma unroll
            for (int ni = 0; ni < 4; ++ni)
                acc[mi][ni] = (f32x4){0.f, 0.f, 0.f, 0.f};

#pragma unroll
        for (int ks = 0; ks < 5; ++ks) {
            bf16x8 a[4];
#pragma unroll
            for (int mi = 0; mi < 4; ++mi)
                a[mi] = *(const bf16x8*)(fab
                        + (size_t)(r0 + mi * 16 + lrow) * KPAD
                        + ks * 32 + g * 8);
#pragma unroll
            for (int mi = 0; mi < 4; ++mi)
#pragma unroll
                for (int ni = 0; ni < 4; ++ni)
                    acc[mi][ni] = __builtin_amdgcn_mfma_f32_16x16x32_bf16(
                        a[mi], bfrag[ni][ks], acc[mi][ni], 0, 0, 0);
        }

        // ---- epilogue: relu(acc + b1) * W2, reduce over hidden.
        // C frag layout: col = lane&15, row = (lane>>4)*4 + reg.
        const int pb = tile & 1;
#pragma unroll
        for (int mi = 0; mi < 4; ++mi) {
            float s[4] = {0.f, 0.f, 0.f, 0.f};
#pragma unroll
            for (int ni = 0; ni < 4; ++ni)
#pragma unroll
                for (int r = 0; r < 4; ++r) {
                    float h = acc[mi][ni][r] + b1v[ni];
                    h = h > 0.f ? h : 0.f;
                    s[r] += h * w2v[ni];
                }
#pragma unroll
            for (int r = 0; r < 4; ++r) {
                for (int off = 1; off < 16; off <<= 1)
                    s[r] += __shfl_xor(s[r], off, 64);
            }
            if (lrow == 0) {
#pragma unroll
                for (int r = 0; r < 4; ++r)
                    partial[pb][wc][wr * 64 + mi * 16 + g * 4 + r] = s[r];
            }
        }
        __syncthreads();
        if (t < 128) {
            int row = b0 + tile * 128 + t;
            float v = partial[pb][0][t] + partial[pb][1][t]
                    + partial[pb][2][t] + partial[pb][3][t]
                    + b2v + f_t[(size_t)row * NF + m];
            out[(size_t)row * NF + m] = v;
        }
        // single barrier per iteration: partial is double-buffered; the
        // combine of tile t happens before the barrier of tile t+1, so
        // writes of tile t+2 (same buffer) can't race it.
    }
}

// ---------------------------------------------------------------------------
extern "C" void kernel_launch(void* const* d_in, const int* in_sizes, int n_in,
                              void* d_out, int out_size, void* d_ws, size_t ws_size,
                              hipStream_t stream) {
    const float* f_t = (const float*)d_in[0];
    const float* a_t = (const float*)d_in[1];
    const float* W1  = (const float*)d_in[2];
    const float* b1  = (const float*)d_in[3];
    const float* W2  = (const float*)d_in[4];
    const float* b2  = (const float*)d_in[5];
    float* out = (float*)d_out;

    __hip_bfloat16* fab = (__hip_bfloat16*)d_ws;   // [4096][160] bf16

    hipLaunchKernelGGL(convert_fa, dim3((BATCH * (KPAD / 8) + 255) / 256),
                       dim3(256), 0, stream, f_t, a_t, fab);
    hipLaunchKernelGGL(fused_mlp, dim3(256), dim3(512), 0, stream,
                       fab, W1, b1, W2, b2, f_t, out);
}

// Round 6
// 76.295 us; speedup vs baseline: 1.7715x; 1.2730x over previous
//
#include <hip/hip_runtime.h>
#include <hip/hip_bf16.h>

// Problem constants
#define BATCH   4096
#define NF      128    // n features == n models
#define NA      16
#define IN_DIM  144    // N_FEATURES + N_ACTIONS
#define KP      160    // w1t K padded to multiple of 32
#define KF      192    // fab K padded so row = 384 B (XOR-swizzle closed)
#define HID     256

typedef __attribute__((ext_vector_type(8))) short bf16x8;
typedef __attribute__((ext_vector_type(4))) float f32x4;
typedef unsigned int u32;

// async global->LDS, 16B per lane. LDS dest must be wave-uniform base + lane*16.
__device__ __forceinline__ void gl_lds16(const void* gsrc, void* ldst) {
    __builtin_amdgcn_global_load_lds(
        (const __attribute__((address_space(1))) u32*)gsrc,
        (__attribute__((address_space(3))) u32*)ldst, 16, 0, 0);
}

// ---------------------------------------------------------------------------
// Kernel 1: fa = concat(f_t, a_t) -> bf16, row padded to KF=192 (zeros), and
// PRE-SWIZZLED: 16B chunk cc of row stored at physical chunk cc ^ (row&7).
// The fused kernel stages rows linearly via global_load_lds and reads frags
// with the matching XOR -> bank-conflict-free ds_read_b128.
__global__ void convert_fa(const float* __restrict__ f_t,
                           const float* __restrict__ a_t,
                           __hip_bfloat16* __restrict__ fab) {
    int c = blockIdx.x * blockDim.x + threadIdx.x;
    const int total = BATCH * (KF / 8);   // 24 chunks per row
    if (c >= total) return;
    int row = c / 24;
    int cc = c - row * 24;
    union { ushort us[8]; uint4 q; } pk;
#pragma unroll
    for (int j = 0; j < 8; ++j) {
        int k = cc * 8 + j;
        float v;
        if (k < NF)           v = f_t[(size_t)row * NF + k];
        else if (k < IN_DIM)  v = a_t[(size_t)row * NA + (k - NF)];
        else                  v = 0.0f;
        __hip_bfloat16 h = __float2bfloat16(v);
        pk.us[j] = *(ushort*)&h;
    }
    int pc = cc ^ (row & 7);              // swizzle: bijective within 24 chunks
    *(uint4*)(fab + (size_t)row * KF + pc * 8) = pk.q;
}

// ---------------------------------------------------------------------------
// Kernel 2: W1 [128][144][256] fp32 -> W1T [128][256][160] bf16 (transposed,
// K zero-padded). Coalesced via LDS transpose.
__global__ void convert_w1t(const float* __restrict__ W1,
                            __hip_bfloat16* __restrict__ w1t) {
    __shared__ float tile[16][HID];
    int bid = blockIdx.x;
    int m = bid / 10;
    int kc = bid - m * 10;
    int t = threadIdx.x;       // 0..255 == output column
    int k0 = kc * 16;
    if (kc < 9) {
#pragma unroll
        for (int i = 0; i < 16; ++i)
            tile[i][t] = W1[((size_t)m * IN_DIM + (k0 + i)) * HID + t];
        __syncthreads();
        union { ushort us[16]; uint4 q[2]; } pk;
#pragma unroll
        for (int i = 0; i < 16; ++i) {
            __hip_bfloat16 h = __float2bfloat16(tile[i][t]);
            pk.us[i] = *(ushort*)&h;
        }
        uint4* dst = (uint4*)(w1t + ((size_t)m * HID + t) * KP + k0);
        dst[0] = pk.q[0];
        dst[1] = pk.q[1];
    } else {
        uint4 z = {0u, 0u, 0u, 0u};
        uint4* dst = (uint4*)(w1t + ((size_t)m * HID + t) * KP + IN_DIM);
        dst[0] = z;
        dst[1] = z;
    }
}

// ---------------------------------------------------------------------------
// Kernel 3: fused grouped MLP.
// Grid 512 = 128 m (bid&127) x 4 batch slices (bid>>7) -> 2 independent
// blocks/CU. Block: 256 thr = 4 waves, wave w owns hidden cols [w*64,w*64+64).
// B (W1T[m]) in registers (80 VGPR/wave), loaded once from w1t via b128.
// A staged in LDS (double-buffered) via global_load_lds from pre-swizzled fab;
// frag reads use matching XOR -> conflict-free.
__global__ __launch_bounds__(256) void fused_mlp(
        const __hip_bfloat16* __restrict__ fab,
        const __hip_bfloat16* __restrict__ w1t,
        const float* __restrict__ b1,
        const float* __restrict__ W2,
        const float* __restrict__ b2,
        const float* __restrict__ f_t,
        float* __restrict__ out) {
    __shared__ __align__(16) __hip_bfloat16 Abuf[2][64 * KF];  // 2 x 24 KB
    __shared__ __align__(16) float partial[2][4][64];          // 2 KB

    const int bid = blockIdx.x;
    const int m     = bid & 127;     // same-m blocks 128 apart -> same XCD L2
    const int slice = bid >> 7;      // 0..3, 1024 rows each
    const int row_base = slice * 1024;
    const int t = threadIdx.x;
    const int w = t >> 6;            // wave = col group 0..3
    const int lane = t & 63;
    const int lrow = lane & 15;
    const int g = lane >> 4;         // 0..3
    const int xr = (lrow & 7) << 4;  // byte XOR for swizzled LDS reads

    // ---- prologue: B-frags from w1t (clean b128 loads), epilogue constants.
    bf16x8 bfrag[4][5];
#pragma unroll
    for (int ni = 0; ni < 4; ++ni) {
        const int col = w * 64 + ni * 16 + lrow;
        const __hip_bfloat16* wp = w1t + ((size_t)m * HID + col) * KP + g * 8;
#pragma unroll
        for (int ks = 0; ks < 5; ++ks)
            bfrag[ni][ks] = *(const bf16x8*)(wp + ks * 32);
    }
    float w2v[4], b1v[4];
#pragma unroll
    for (int ni = 0; ni < 4; ++ni) {
        int col = w * 64 + ni * 16 + lrow;
        w2v[ni] = W2[(size_t)m * HID + col];
        b1v[ni] = b1[(size_t)m * HID + col];
    }
    const float b2v = b2[m];

    // ---- stage tile 0 (linear 24 KB copy; fab is pre-swizzled).
    {
        const char* src = (const char*)(fab + (size_t)row_base * KF);
        char* dst = (char*)&Abuf[0][0];
#pragma unroll
        for (int i = 0; i < 6; ++i)
            gl_lds16(src + (size_t)(t + i * 256) * 16, dst + (t + i * 256) * 16);
    }
    __syncthreads();

    for (int tile = 0; tile < 16; ++tile) {
        const int cur = tile & 1;
        const int r0 = row_base + tile * 64;

        // issue next tile's stage early (drained by this tile's barrier)
        if (tile < 15) {
            const char* src = (const char*)(fab + (size_t)(r0 + 64) * KF);
            char* dst = (char*)&Abuf[cur ^ 1][0];
#pragma unroll
            for (int i = 0; i < 6; ++i)
                gl_lds16(src + (size_t)(t + i * 256) * 16, dst + (t + i * 256) * 16);
        }
        // hoisted skip-connection gather (latency hidden under K-loop)
        float skipv = 0.0f;
        if (t < 64) skipv = f_t[(size_t)(r0 + t) * NF + m];

        f32x4 acc[4][4];
#pragma unroll
        for (int mi = 0; mi < 4; ++mi)
#pragma unroll
            for (int ni = 0; ni < 4; ++ni)
                acc[mi][ni] = (f32x4){0.f, 0.f, 0.f, 0.f};

        const char* ab = (const char*)&Abuf[cur][0];
#pragma unroll
        for (int ks = 0; ks < 5; ++ks) {
            bf16x8 a[4];
#pragma unroll
            for (int mi = 0; mi < 4; ++mi) {
                int off = (mi * 16 + lrow) * 384 + ((ks * 64 + g * 16) ^ xr);
                a[mi] = *(const bf16x8*)(ab + off);
            }
#pragma unroll
            for (int mi = 0; mi < 4; ++mi)
#pragma unroll
                for (int ni = 0; ni < 4; ++ni)
                    acc[mi][ni] = __builtin_amdgcn_mfma_f32_16x16x32_bf16(
                        a[mi], bfrag[ni][ks], acc[mi][ni], 0, 0, 0);
        }

        // ---- epilogue: relu(acc + b1) * W2, reduce over hidden cols.
        // C frag layout: col = lane&15, row = (lane>>4)*4 + reg.
#pragma unroll
        for (int mi = 0; mi < 4; ++mi) {
            float s[4] = {0.f, 0.f, 0.f, 0.f};
#pragma unroll
            for (int ni = 0; ni < 4; ++ni)
#pragma unroll
                for (int r = 0; r < 4; ++r) {
                    float h = acc[mi][ni][r] + b1v[ni];
                    h = h > 0.f ? h : 0.f;
                    s[r] += h * w2v[ni];
                }
#pragma unroll
            for (int r = 0; r < 4; ++r) {
                for (int off = 1; off < 16; off <<= 1)
                    s[r] += __shfl_xor(s[r], off, 64);
            }
            if (lrow == 0) {
                float4 sv = make_float4(s[0], s[1], s[2], s[3]);
                *(float4*)&partial[cur][w][mi * 16 + g * 4] = sv;
            }
        }
        __syncthreads();   // partial ready; stage(tile+1) drained; Abuf[cur] free
        if (t < 64) {
            float v = partial[cur][0][t] + partial[cur][1][t]
                    + partial[cur][2][t] + partial[cur][3][t]
                    + b2v + skipv;
            out[(size_t)(r0 + t) * NF + m] = v;
        }
    }
}

// ---------------------------------------------------------------------------
extern "C" void kernel_launch(void* const* d_in, const int* in_sizes, int n_in,
                              void* d_out, int out_size, void* d_ws, size_t ws_size,
                              hipStream_t stream) {
    const float* f_t = (const float*)d_in[0];
    const float* a_t = (const float*)d_in[1];
    const float* W1  = (const float*)d_in[2];
    const float* b1  = (const float*)d_in[3];
    const float* W2  = (const float*)d_in[4];
    const float* b2  = (const float*)d_in[5];
    float* out = (float*)d_out;

    // ws layout: w1t bf16 [128][256][160] (10.49 MB), fab bf16 [4096][192] (1.57 MB)
    __hip_bfloat16* w1t = (__hip_bfloat16*)d_ws;
    __hip_bfloat16* fab = (__hip_bfloat16*)((char*)d_ws + (size_t)NF * HID * KP * 2);

    hipLaunchKernelGGL(convert_w1t, dim3(NF * 10), dim3(256), 0, stream, W1, w1t);
    hipLaunchKernelGGL(convert_fa, dim3((BATCH * (KF / 8) + 255) / 256), dim3(256),
                       0, stream, f_t, a_t, fab);
    hipLaunchKernelGGL(fused_mlp, dim3(512), dim3(256), 0, stream,
                       fab, w1t, b1, W2, b2, f_t, out);
}

// Round 7
// 60.728 us; speedup vs baseline: 2.2256x; 1.2563x over previous
//
#include <hip/hip_runtime.h>
#include <hip/hip_bf16.h>

// Problem constants
#define BATCH   4096
#define NF      128    // n features == n models
#define NA      16
#define IN_DIM  144    // N_FEATURES + N_ACTIONS
#define KP      160    // w1t K padded to multiple of 32 (col 144 carries b1)
#define KF      192    // fab K padded so row = 384 B (XOR-swizzle closed)
#define HID     256

typedef __attribute__((ext_vector_type(8))) short bf16x8;
typedef __attribute__((ext_vector_type(4))) float f32x4;
typedef unsigned int u32;

// async global->LDS, 16B per lane. LDS dest must be wave-uniform base + lane*16.
__device__ __forceinline__ void gl_lds16(const void* gsrc, void* ldst) {
    __builtin_amdgcn_global_load_lds(
        (const __attribute__((address_space(1))) u32*)gsrc,
        (__attribute__((address_space(3))) u32*)ldst, 16, 0, 0);
}

// ---------------------------------------------------------------------------
// Kernel 1: fa = concat(f_t, a_t, 1.0, 0...) -> bf16, row padded to KF=192,
// PRE-SWIZZLED: 16B chunk cc of row stored at physical chunk cc ^ (row&7).
// Col 144 = 1.0 so the GEMM accumulates b1 (stored in w1t col 144).
__global__ void convert_fa(const float* __restrict__ f_t,
                           const float* __restrict__ a_t,
                           __hip_bfloat16* __restrict__ fab) {
    int c = blockIdx.x * blockDim.x + threadIdx.x;
    const int total = BATCH * (KF / 8);   // 24 chunks per row
    if (c >= total) return;
    int row = c / 24;
    int cc = c - row * 24;
    union { ushort us[8]; uint4 q; } pk;
#pragma unroll
    for (int j = 0; j < 8; ++j) {
        int k = cc * 8 + j;
        float v;
        if (k < NF)            v = f_t[(size_t)row * NF + k];
        else if (k < IN_DIM)   v = a_t[(size_t)row * NA + (k - NF)];
        else if (k == IN_DIM)  v = 1.0f;   // bias lane
        else                   v = 0.0f;
        __hip_bfloat16 h = __float2bfloat16(v);
        pk.us[j] = *(ushort*)&h;
    }
    int pc = cc ^ (row & 7);              // swizzle: bijective within 24 chunks
    *(uint4*)(fab + (size_t)row * KF + pc * 8) = pk.q;
}

// ---------------------------------------------------------------------------
// Kernel 2: W1 [128][144][256] fp32 -> W1T [128][256][160] bf16 (transposed,
// K zero-padded; col 144 := b1 so GEMM adds the bias). Coalesced via LDS.
__global__ void convert_w1t(const float* __restrict__ W1,
                            const float* __restrict__ b1,
                            __hip_bfloat16* __restrict__ w1t) {
    __shared__ float tile[16][HID];
    int bid = blockIdx.x;
    int m = bid / 10;
    int kc = bid - m * 10;
    int t = threadIdx.x;       // 0..255 == output column
    int k0 = kc * 16;
    if (kc < 9) {
#pragma unroll
        for (int i = 0; i < 16; ++i)
            tile[i][t] = W1[((size_t)m * IN_DIM + (k0 + i)) * HID + t];
        __syncthreads();
        union { ushort us[16]; uint4 q[2]; } pk;
#pragma unroll
        for (int i = 0; i < 16; ++i) {
            __hip_bfloat16 h = __float2bfloat16(tile[i][t]);
            pk.us[i] = *(ushort*)&h;
        }
        uint4* dst = (uint4*)(w1t + ((size_t)m * HID + t) * KP + k0);
        dst[0] = pk.q[0];
        dst[1] = pk.q[1];
    } else {
        // pad region k = 144..159: k=144 carries b1, rest zero.
        union { ushort us[8]; uint4 q; } pk;
#pragma unroll
        for (int j = 0; j < 8; ++j) pk.us[j] = 0;
        __hip_bfloat16 hb = __float2bfloat16(b1[(size_t)m * HID + t]);
        pk.us[0] = *(ushort*)&hb;
        uint4 z = {0u, 0u, 0u, 0u};
        uint4* dst = (uint4*)(w1t + ((size_t)m * HID + t) * KP + IN_DIM);
        dst[0] = pk.q;
        dst[1] = z;
    }
}

// ---------------------------------------------------------------------------
// Kernel 3: fused grouped MLP, SWAPPED-operand layer-1 MFMA.
// mfma(A=W1T-frag, B=fa-frag): D[m=hid][n=batch] -> lane holds, per (hi,bj),
// H[batch = bj*16 + (lane&15)][hid = hi*16 + g*4 + r]. The hidden-reduce is
// then 16 in-register max+fma per batch row + 2 shallow shuffles (xor16,32),
// replacing R6's 4-deep 16-lane shuffle chains (64 ds_swizzle -> 8).
// Grid 512 = 128 m x 4 slices; 256 thr = 4 waves; wave owns 64 hid cols.
__global__ __launch_bounds__(256) void fused_mlp(
        const __hip_bfloat16* __restrict__ fab,
        const __hip_bfloat16* __restrict__ w1t,
        const float* __restrict__ W2,
        const float* __restrict__ b2,
        const float* __restrict__ f_t,
        float* __restrict__ out) {
    __shared__ __align__(16) __hip_bfloat16 Abuf[2][64 * KF];  // 2 x 24 KB
    __shared__ __align__(16) float partial[2][4][64];          // 2 KB

    const int bid = blockIdx.x;
    const int m     = bid & 127;     // same-m blocks 128 apart -> same XCD L2
    const int slice = bid >> 7;      // 0..3, 1024 rows each
    const int row_base = slice * 1024;
    const int t = threadIdx.x;
    const int w = t >> 6;            // wave = hid col group 0..3
    const int lane = t & 63;
    const int lrow = lane & 15;
    const int g = lane >> 4;         // 0..3
    const int xr = (lrow & 7) << 4;  // byte XOR for swizzled LDS reads

    // ---- prologue: W1T frags (used as MFMA *A* operand), W2 per-lane.
    // frag layout: hid = lane&15 (+16*hi), k = g*8 + j (+32*ks). Identical
    // load as R6; only the mfma operand position changes.
    bf16x8 bfrag[4][5];
#pragma unroll
    for (int hi = 0; hi < 4; ++hi) {
        const int col = w * 64 + hi * 16 + lrow;
        const __hip_bfloat16* wp = w1t + ((size_t)m * HID + col) * KP + g * 8;
#pragma unroll
        for (int ks = 0; ks < 5; ++ks)
            bfrag[hi][ks] = *(const bf16x8*)(wp + ks * 32);
    }
    // w2v[hi][r] = W2[m][w*64 + hi*16 + g*4 + r]  (vector f32x4 loads)
    f32x4 w2v[4];
#pragma unroll
    for (int hi = 0; hi < 4; ++hi)
        w2v[hi] = *(const f32x4*)(W2 + (size_t)m * HID + w * 64 + hi * 16 + g * 4);
    const float b2v = b2[m];

    // ---- stage tile 0 (linear 24 KB copy; fab is pre-swizzled).
    {
        const char* src = (const char*)(fab + (size_t)row_base * KF);
        char* dst = (char*)&Abuf[0][0];
#pragma unroll
        for (int i = 0; i < 6; ++i)
            gl_lds16(src + (size_t)(t + i * 256) * 16, dst + (t + i * 256) * 16);
    }
    __syncthreads();

    for (int tile = 0; tile < 16; ++tile) {
        const int cur = tile & 1;
        const int r0 = row_base + tile * 64;

        // issue next tile's stage early (drained by this tile's barrier)
        if (tile < 15) {
            const char* src = (const char*)(fab + (size_t)(r0 + 64) * KF);
            char* dst = (char*)&Abuf[cur ^ 1][0];
#pragma unroll
            for (int i = 0; i < 6; ++i)
                gl_lds16(src + (size_t)(t + i * 256) * 16, dst + (t + i * 256) * 16);
        }
        // hoisted skip-connection gather (latency hidden under K-loop)
        float skipv = 0.0f;
        if (t < 64) skipv = f_t[(size_t)(r0 + t) * NF + m];

        f32x4 acc[4][4];   // [hi][bj]
#pragma unroll
        for (int hi = 0; hi < 4; ++hi)
#pragma unroll
            for (int bj = 0; bj < 4; ++bj)
                acc[hi][bj] = (f32x4){0.f, 0.f, 0.f, 0.f};

        const char* ab = (const char*)&Abuf[cur][0];
#pragma unroll
        for (int ks = 0; ks < 5; ++ks) {
            bf16x8 a[4];   // fa frag: batch = bj*16 + lrow, k = ks*32 + g*8
#pragma unroll
            for (int bj = 0; bj < 4; ++bj) {
                int off = (bj * 16 + lrow) * 384 + ((ks * 64 + g * 16) ^ xr);
                a[bj] = *(const bf16x8*)(ab + off);
            }
#pragma unroll
            for (int hi = 0; hi < 4; ++hi)
#pragma unroll
                for (int bj = 0; bj < 4; ++bj)
                    acc[hi][bj] = __builtin_amdgcn_mfma_f32_16x16x32_bf16(
                        bfrag[hi][ks], a[bj], acc[hi][bj], 0, 0, 0);
        }

        // ---- epilogue: relu(acc) * W2 (b1 already folded into GEMM).
        // lane holds H[batch = bj*16+lrow][hid = hi*16+g*4+r].
        float sarr[4];
#pragma unroll
        for (int bj = 0; bj < 4; ++bj) {
            float s = 0.f;
#pragma unroll
            for (int hi = 0; hi < 4; ++hi)
#pragma unroll
                for (int r = 0; r < 4; ++r) {
                    float h = acc[hi][bj][r];
                    h = h > 0.f ? h : 0.f;
                    s = fmaf(h, w2v[hi][r], s);
                }
            // sum the 4 g-groups (hid quarters): shallow 2-step reduce
            s += __shfl_xor(s, 16, 64);
            s += __shfl_xor(s, 32, 64);
            sarr[bj] = s;
        }
        // lane (g*16 + lrow) stores batch row g*16+lrow -> pick bj == g
        float sv = (g == 0) ? sarr[0] : (g == 1) ? sarr[1]
                 : (g == 2) ? sarr[2] : sarr[3];
        partial[cur][w][lane] = sv;

        __syncthreads();   // partial ready; stage(tile+1) drained; Abuf[cur] free
        if (t < 64) {
            float v = partial[cur][0][t] + partial[cur][1][t]
                    + partial[cur][2][t] + partial[cur][3][t]
                    + b2v + skipv;
            out[(size_t)(r0 + t) * NF + m] = v;
        }
    }
}

// ---------------------------------------------------------------------------
extern "C" void kernel_launch(void* const* d_in, const int* in_sizes, int n_in,
                              void* d_out, int out_size, void* d_ws, size_t ws_size,
                              hipStream_t stream) {
    const float* f_t = (const float*)d_in[0];
    const float* a_t = (const float*)d_in[1];
    const float* W1  = (const float*)d_in[2];
    const float* b1  = (const float*)d_in[3];
    const float* W2  = (const float*)d_in[4];
    const float* b2  = (const float*)d_in[5];
    float* out = (float*)d_out;

    // ws layout: w1t bf16 [128][256][160] (10.49 MB), fab bf16 [4096][192] (1.57 MB)
    __hip_bfloat16* w1t = (__hip_bfloat16*)d_ws;
    __hip_bfloat16* fab = (__hip_bfloat16*)((char*)d_ws + (size_t)NF * HID * KP * 2);

    hipLaunchKernelGGL(convert_w1t, dim3(NF * 10), dim3(256), 0, stream, W1, b1, w1t);
    hipLaunchKernelGGL(convert_fa, dim3((BATCH * (KF / 8) + 255) / 256), dim3(256),
                       0, stream, f_t, a_t, fab);
    hipLaunchKernelGGL(fused_mlp, dim3(512), dim3(256), 0, stream,
                       fab, w1t, W2, b2, f_t, out);
}

// Round 8
// 60.576 us; speedup vs baseline: 2.2312x; 1.0025x over previous
//
#include <hip/hip_runtime.h>
#include <hip/hip_bf16.h>

// Problem constants
#define BATCH   4096
#define NF      128    // n features == n models
#define NA      16
#define IN_DIM  144    // N_FEATURES + N_ACTIONS
#define KP      160    // w1t K padded to multiple of 32 (col 144 carries b1)
#define KF      192    // fab K padded so row = 384 B (XOR-swizzle closed)
#define HID     256

typedef __attribute__((ext_vector_type(8))) short bf16x8;
typedef __attribute__((ext_vector_type(4))) float f32x4;
typedef unsigned int u32;

// async global->LDS, 16B per lane. LDS dest must be wave-uniform base + lane*16.
__device__ __forceinline__ void gl_lds16(const void* gsrc, void* ldst) {
    __builtin_amdgcn_global_load_lds(
        (const __attribute__((address_space(1))) u32*)gsrc,
        (__attribute__((address_space(3))) u32*)ldst, 16, 0, 0);
}

// ---------------------------------------------------------------------------
// Merged convert kernel (one launch instead of two):
//   blocks [0, 1280):      W1 [128][144][256] fp32 -> w1t [128][256][160] bf16
//                          (transposed, col 144 := b1 -> GEMM adds bias)
//   blocks [1280, 1664):   fa = concat(f_t, a_t, 1.0, 0pad) -> bf16 [4096][192],
//                          pre-swizzled: chunk cc stored at cc ^ (row&7)
__global__ void convert_all(const float* __restrict__ W1,
                            const float* __restrict__ b1,
                            const float* __restrict__ f_t,
                            const float* __restrict__ a_t,
                            __hip_bfloat16* __restrict__ w1t,
                            __hip_bfloat16* __restrict__ fab) {
    const int bid = blockIdx.x;
    const int t = threadIdx.x;
    if (bid < 1280) {
        __shared__ float tile[16][HID];
        int m = bid / 10;
        int kc = bid - m * 10;
        int k0 = kc * 16;
        if (kc < 9) {
#pragma unroll
            for (int i = 0; i < 16; ++i)
                tile[i][t] = W1[((size_t)m * IN_DIM + (k0 + i)) * HID + t];
            __syncthreads();
            union { ushort us[16]; uint4 q[2]; } pk;
#pragma unroll
            for (int i = 0; i < 16; ++i) {
                __hip_bfloat16 h = __float2bfloat16(tile[i][t]);
                pk.us[i] = *(ushort*)&h;
            }
            uint4* dst = (uint4*)(w1t + ((size_t)m * HID + t) * KP + k0);
            dst[0] = pk.q[0];
            dst[1] = pk.q[1];
        } else {
            // pad region k = 144..159: k=144 carries b1, rest zero.
            union { ushort us[8]; uint4 q; } pk;
#pragma unroll
            for (int j = 0; j < 8; ++j) pk.us[j] = 0;
            __hip_bfloat16 hb = __float2bfloat16(b1[(size_t)m * HID + t]);
            pk.us[0] = *(ushort*)&hb;
            uint4 z = {0u, 0u, 0u, 0u};
            uint4* dst = (uint4*)(w1t + ((size_t)m * HID + t) * KP + IN_DIM);
            dst[0] = pk.q;
            dst[1] = z;
        }
    } else {
        int c = (bid - 1280) * 256 + t;
        const int total = BATCH * (KF / 8);   // 24 chunks per row
        if (c >= total) return;
        int row = c / 24;
        int cc = c - row * 24;
        union { ushort us[8]; uint4 q; } pk;
#pragma unroll
        for (int j = 0; j < 8; ++j) {
            int k = cc * 8 + j;
            float v;
            if (k < NF)            v = f_t[(size_t)row * NF + k];
            else if (k < IN_DIM)   v = a_t[(size_t)row * NA + (k - NF)];
            else if (k == IN_DIM)  v = 1.0f;   // bias lane
            else                   v = 0.0f;
            __hip_bfloat16 h = __float2bfloat16(v);
            pk.us[j] = *(ushort*)&h;
        }
        int pc = cc ^ (row & 7);              // bijective within 24 chunks
        *(uint4*)(fab + (size_t)row * KF + pc * 8) = pk.q;
    }
}

// ---------------------------------------------------------------------------
// Fused grouped MLP, swapped-operand layer-1 MFMA.
// Grid 1024 = 128 m (bid&127) x 8 slices (bid>>7) of 512 rows (8 tiles of 64)
// -> 3 blocks/CU resident (LDS-limited), 3 waves/SIMD for pipe overlap.
// mfma(A=W1T-frag, B=fa-frag): lane holds H[batch=bj*16+(lane&15)]
// [hid=hi*16+g*4+r]; hidden-reduce = in-register fma + 2 shallow shuffles.
__global__ __launch_bounds__(256) void fused_mlp(
        const __hip_bfloat16* __restrict__ fab,
        const __hip_bfloat16* __restrict__ w1t,
        const float* __restrict__ W2,
        const float* __restrict__ b2,
        const float* __restrict__ f_t,
        float* __restrict__ out) {
    __shared__ __align__(16) __hip_bfloat16 Abuf[2][64 * KF];  // 2 x 24 KB
    __shared__ __align__(16) float partial[2][4][64];          // 2 KB

    const int bid = blockIdx.x;
    const int m     = bid & 127;     // same-m blocks 128 apart -> same XCD L2
    const int slice = bid >> 7;      // 0..7, 512 rows each
    const int row_base = slice * 512;
    const int t = threadIdx.x;
    const int w = t >> 6;            // wave = hid col group 0..3
    const int lane = t & 63;
    const int lrow = lane & 15;
    const int g = lane >> 4;         // 0..3
    const int xr = (lrow & 7) << 4;  // byte XOR for swizzled LDS reads

    // ---- prologue: W1T frags (MFMA A operand), W2 per-lane f32x4.
    bf16x8 bfrag[4][5];
#pragma unroll
    for (int hi = 0; hi < 4; ++hi) {
        const int col = w * 64 + hi * 16 + lrow;
        const __hip_bfloat16* wp = w1t + ((size_t)m * HID + col) * KP + g * 8;
#pragma unroll
        for (int ks = 0; ks < 5; ++ks)
            bfrag[hi][ks] = *(const bf16x8*)(wp + ks * 32);
    }
    f32x4 w2v[4];
#pragma unroll
    for (int hi = 0; hi < 4; ++hi)
        w2v[hi] = *(const f32x4*)(W2 + (size_t)m * HID + w * 64 + hi * 16 + g * 4);
    const float b2v = b2[m];

    // ---- stage tile 0 (linear 24 KB copy; fab is pre-swizzled).
    {
        const char* src = (const char*)(fab + (size_t)row_base * KF);
        char* dst = (char*)&Abuf[0][0];
#pragma unroll
        for (int i = 0; i < 6; ++i)
            gl_lds16(src + (size_t)(t + i * 256) * 16, dst + (t + i * 256) * 16);
    }
    __syncthreads();

    for (int tile = 0; tile < 8; ++tile) {
        const int cur = tile & 1;
        const int r0 = row_base + tile * 64;

        // issue next tile's stage early (drained by this tile's barrier)
        if (tile < 7) {
            const char* src = (const char*)(fab + (size_t)(r0 + 64) * KF);
            char* dst = (char*)&Abuf[cur ^ 1][0];
#pragma unroll
            for (int i = 0; i < 6; ++i)
                gl_lds16(src + (size_t)(t + i * 256) * 16, dst + (t + i * 256) * 16);
        }
        // hoisted skip-connection gather (latency hidden under K-loop)
        float skipv = 0.0f;
        if (t < 64) skipv = f_t[(size_t)(r0 + t) * NF + m];

        f32x4 acc[4][4];   // [hi][bj]
#pragma unroll
        for (int hi = 0; hi < 4; ++hi)
#pragma unroll
            for (int bj = 0; bj < 4; ++bj)
                acc[hi][bj] = (f32x4){0.f, 0.f, 0.f, 0.f};

        const char* ab = (const char*)&Abuf[cur][0];
#pragma unroll
        for (int ks = 0; ks < 5; ++ks) {
            bf16x8 a[4];   // fa frag: batch = bj*16 + lrow, k = ks*32 + g*8
#pragma unroll
            for (int bj = 0; bj < 4; ++bj) {
                int off = (bj * 16 + lrow) * 384 + ((ks * 64 + g * 16) ^ xr);
                a[bj] = *(const bf16x8*)(ab + off);
            }
#pragma unroll
            for (int hi = 0; hi < 4; ++hi)
#pragma unroll
                for (int bj = 0; bj < 4; ++bj)
                    acc[hi][bj] = __builtin_amdgcn_mfma_f32_16x16x32_bf16(
                        bfrag[hi][ks], a[bj], acc[hi][bj], 0, 0, 0);
        }

        // ---- epilogue: relu(acc) * W2 (b1 folded into GEMM). 4 independent
        // per-r accumulators -> dep chain 4 fma + 2 add (was 16 fma).
        float sarr[4];
#pragma unroll
        for (int bj = 0; bj < 4; ++bj) {
            float sr0 = 0.f, sr1 = 0.f, sr2 = 0.f, sr3 = 0.f;
#pragma unroll
            for (int hi = 0; hi < 4; ++hi) {
                float h0 = acc[hi][bj][0]; h0 = h0 > 0.f ? h0 : 0.f;
                float h1 = acc[hi][bj][1]; h1 = h1 > 0.f ? h1 : 0.f;
                float h2 = acc[hi][bj][2]; h2 = h2 > 0.f ? h2 : 0.f;
                float h3 = acc[hi][bj][3]; h3 = h3 > 0.f ? h3 : 0.f;
                sr0 = fmaf(h0, w2v[hi][0], sr0);
                sr1 = fmaf(h1, w2v[hi][1], sr1);
                sr2 = fmaf(h2, w2v[hi][2], sr2);
                sr3 = fmaf(h3, w2v[hi][3], sr3);
            }
            float s = (sr0 + sr1) + (sr2 + sr3);
            s += __shfl_xor(s, 16, 64);
            s += __shfl_xor(s, 32, 64);
            sarr[bj] = s;
        }
        // lane (g*16 + lrow) stores batch row g*16+lrow -> pick bj == g
        float sv = (g == 0) ? sarr[0] : (g == 1) ? sarr[1]
                 : (g == 2) ? sarr[2] : sarr[3];
        partial[cur][w][lane] = sv;

        __syncthreads();   // partial ready; stage(tile+1) drained; Abuf[cur] free
        if (t < 64) {
            float v = partial[cur][0][t] + partial[cur][1][t]
                    + partial[cur][2][t] + partial[cur][3][t]
                    + b2v + skipv;
            out[(size_t)(r0 + t) * NF + m] = v;
        }
    }
}

// ---------------------------------------------------------------------------
extern "C" void kernel_launch(void* const* d_in, const int* in_sizes, int n_in,
                              void* d_out, int out_size, void* d_ws, size_t ws_size,
                              hipStream_t stream) {
    const float* f_t = (const float*)d_in[0];
    const float* a_t = (const float*)d_in[1];
    const float* W1  = (const float*)d_in[2];
    const float* b1  = (const float*)d_in[3];
    const float* W2  = (const float*)d_in[4];
    const float* b2  = (const float*)d_in[5];
    float* out = (float*)d_out;

    // ws layout: w1t bf16 [128][256][160] (10.49 MB), fab bf16 [4096][192] (1.57 MB)
    __hip_bfloat16* w1t = (__hip_bfloat16*)d_ws;
    __hip_bfloat16* fab = (__hip_bfloat16*)((char*)d_ws + (size_t)NF * HID * KP * 2);

    // converts merged: 1280 w1t blocks + 384 fa blocks
    hipLaunchKernelGGL(convert_all, dim3(1664), dim3(256), 0, stream,
                       W1, b1, f_t, a_t, w1t, fab);
    hipLaunchKernelGGL(fused_mlp, dim3(1024), dim3(256), 0, stream,
                       fab, w1t, W2, b2, f_t, out);
}

// Round 9
// 57.771 us; speedup vs baseline: 2.3395x; 1.0486x over previous
//
#include <hip/hip_runtime.h>
#include <hip/hip_bf16.h>

// Problem constants
#define BATCH   4096
#define NF      128    // n features == n models
#define NA      16
#define IN_DIM  144    // N_FEATURES + N_ACTIONS
#define KP      160    // w1t K padded to multiple of 32 (col 144 carries b1)
#define KF      192    // fab K padded so row = 384 B (XOR-swizzle closed)
#define HID     256

typedef __attribute__((ext_vector_type(8))) short bf16x8;
typedef __attribute__((ext_vector_type(4))) float f32x4;
typedef unsigned int u32;

// async global->LDS, 16B per lane. LDS dest must be wave-uniform base + lane*16.
__device__ __forceinline__ void gl_lds16(const void* gsrc, void* ldst) {
    __builtin_amdgcn_global_load_lds(
        (const __attribute__((address_space(1))) u32*)gsrc,
        (__attribute__((address_space(3))) u32*)ldst, 16, 0, 0);
}

// ---------------------------------------------------------------------------
// Merged convert kernel:
//   blocks [0, 1280):      W1 [128][144][256] fp32 -> w1t [128][256][160] bf16
//                          (transposed, col 144 := b1 -> GEMM adds bias)
//   blocks [1280, 1664):   fa = concat(f_t, a_t, 1.0, 0pad) -> bf16 [4096][192],
//                          pre-swizzled: chunk cc stored at cc ^ (row&7)
__global__ void convert_all(const float* __restrict__ W1,
                            const float* __restrict__ b1,
                            const float* __restrict__ f_t,
                            const float* __restrict__ a_t,
                            __hip_bfloat16* __restrict__ w1t,
                            __hip_bfloat16* __restrict__ fab) {
    const int bid = blockIdx.x;
    const int t = threadIdx.x;
    if (bid < 1280) {
        __shared__ float tile[16][HID];
        int m = bid / 10;
        int kc = bid - m * 10;
        int k0 = kc * 16;
        if (kc < 9) {
#pragma unroll
            for (int i = 0; i < 16; ++i)
                tile[i][t] = W1[((size_t)m * IN_DIM + (k0 + i)) * HID + t];
            __syncthreads();
            union { ushort us[16]; uint4 q[2]; } pk;
#pragma unroll
            for (int i = 0; i < 16; ++i) {
                __hip_bfloat16 h = __float2bfloat16(tile[i][t]);
                pk.us[i] = *(ushort*)&h;
            }
            uint4* dst = (uint4*)(w1t + ((size_t)m * HID + t) * KP + k0);
            dst[0] = pk.q[0];
            dst[1] = pk.q[1];
        } else {
            // pad region k = 144..159: k=144 carries b1, rest zero.
            union { ushort us[8]; uint4 q; } pk;
#pragma unroll
            for (int j = 0; j < 8; ++j) pk.us[j] = 0;
            __hip_bfloat16 hb = __float2bfloat16(b1[(size_t)m * HID + t]);
            pk.us[0] = *(ushort*)&hb;
            uint4 z = {0u, 0u, 0u, 0u};
            uint4* dst = (uint4*)(w1t + ((size_t)m * HID + t) * KP + IN_DIM);
            dst[0] = pk.q;
            dst[1] = z;
        }
    } else {
        int c = (bid - 1280) * 256 + t;
        const int total = BATCH * (KF / 8);   // 24 chunks per row
        if (c >= total) return;
        int row = c / 24;
        int cc = c - row * 24;
        union { ushort us[8]; uint4 q; } pk;
#pragma unroll
        for (int j = 0; j < 8; ++j) {
            int k = cc * 8 + j;
            float v;
            if (k < NF)            v = f_t[(size_t)row * NF + k];
            else if (k < IN_DIM)   v = a_t[(size_t)row * NA + (k - NF)];
            else if (k == IN_DIM)  v = 1.0f;   // bias lane
            else                   v = 0.0f;
            __hip_bfloat16 h = __float2bfloat16(v);
            pk.us[j] = *(ushort*)&h;
        }
        int pc = cc ^ (row & 7);              // bijective within 24 chunks
        *(uint4*)(fab + (size_t)row * KF + pc * 8) = pk.q;
    }
}

// ---------------------------------------------------------------------------
// Fused grouped MLP, swapped-operand layer-1 MFMA, 8-wave blocks.
// Grid 512 = 128 m (bid&127) x 4 slices (bid>>7) of 1024 rows (16 tiles of 64).
// 512 thr = 8 waves; wave w owns hid cols [w*32, w*32+32) -> 2 blocks/CU
// x 8 waves = 4 waves/SIMD for cross-wave MFMA/VALU/LDS overlap.
// mfma(A=W1T-frag, B=fa-frag): lane holds H[batch=bj*16+(lane&15)]
// [hid=hi*16+g*4+r]; hidden-reduce = in-register fma + 2 shallow shuffles.
__global__ __launch_bounds__(512, 4) void fused_mlp(
        const __hip_bfloat16* __restrict__ fab,
        const __hip_bfloat16* __restrict__ w1t,
        const float* __restrict__ W2,
        const float* __restrict__ b2,
        const float* __restrict__ f_t,
        float* __restrict__ out) {
    __shared__ __align__(16) __hip_bfloat16 Abuf[2][64 * KF];  // 2 x 24 KB
    __shared__ __align__(16) float partial[2][8][64];          // 4 KB

    const int bid = blockIdx.x;
    const int m     = bid & 127;     // same-m blocks 128 apart -> same XCD L2
    const int slice = bid >> 7;      // 0..3, 1024 rows each
    const int row_base = slice * 1024;
    const int t = threadIdx.x;
    const int w = t >> 6;            // wave = hid col group 0..7 (32 cols each)
    const int lane = t & 63;
    const int lrow = lane & 15;
    const int g = lane >> 4;         // 0..3
    const int xr = (lrow & 7) << 4;  // byte XOR for swizzled LDS reads

    // ---- prologue: W1T frags (MFMA A operand), W2 per-lane f32x4.
    bf16x8 bfrag[2][5];
#pragma unroll
    for (int hi = 0; hi < 2; ++hi) {
        const int col = w * 32 + hi * 16 + lrow;
        const __hip_bfloat16* wp = w1t + ((size_t)m * HID + col) * KP + g * 8;
#pragma unroll
        for (int ks = 0; ks < 5; ++ks)
            bfrag[hi][ks] = *(const bf16x8*)(wp + ks * 32);
    }
    f32x4 w2v[2];
#pragma unroll
    for (int hi = 0; hi < 2; ++hi)
        w2v[hi] = *(const f32x4*)(W2 + (size_t)m * HID + w * 32 + hi * 16 + g * 4);
    const float b2v = b2[m];

    // ---- stage tile 0 (linear 24 KB copy; fab is pre-swizzled).
    {
        const char* src = (const char*)(fab + (size_t)row_base * KF);
        char* dst = (char*)&Abuf[0][0];
#pragma unroll
        for (int i = 0; i < 3; ++i)
            gl_lds16(src + (size_t)(t + i * 512) * 16, dst + (t + i * 512) * 16);
    }
    __syncthreads();

    for (int tile = 0; tile < 16; ++tile) {
        const int cur = tile & 1;
        const int r0 = row_base + tile * 64;

        // issue next tile's stage early (drained by this tile's barrier)
        if (tile < 15) {
            const char* src = (const char*)(fab + (size_t)(r0 + 64) * KF);
            char* dst = (char*)&Abuf[cur ^ 1][0];
#pragma unroll
            for (int i = 0; i < 3; ++i)
                gl_lds16(src + (size_t)(t + i * 512) * 16, dst + (t + i * 512) * 16);
        }
        // hoisted skip-connection gather (latency hidden under K-loop)
        float skipv = 0.0f;
        if (t < 64) skipv = f_t[(size_t)(r0 + t) * NF + m];

        f32x4 acc[2][4];   // [hi][bj]
#pragma unroll
        for (int hi = 0; hi < 2; ++hi)
#pragma unroll
            for (int bj = 0; bj < 4; ++bj)
                acc[hi][bj] = (f32x4){0.f, 0.f, 0.f, 0.f};

        const char* ab = (const char*)&Abuf[cur][0];
#pragma unroll
        for (int ks = 0; ks < 5; ++ks) {
            bf16x8 a[4];   // fa frag: batch = bj*16 + lrow, k = ks*32 + g*8
#pragma unroll
            for (int bj = 0; bj < 4; ++bj) {
                int off = (bj * 16 + lrow) * 384 + ((ks * 64 + g * 16) ^ xr);
                a[bj] = *(const bf16x8*)(ab + off);
            }
#pragma unroll
            for (int hi = 0; hi < 2; ++hi)
#pragma unroll
                for (int bj = 0; bj < 4; ++bj)
                    acc[hi][bj] = __builtin_amdgcn_mfma_f32_16x16x32_bf16(
                        bfrag[hi][ks], a[bj], acc[hi][bj], 0, 0, 0);
        }

        // ---- epilogue: relu(acc) * W2 (b1 folded into GEMM). 4 independent
        // per-r accumulators -> shallow dep chains.
        float sarr[4];
#pragma unroll
        for (int bj = 0; bj < 4; ++bj) {
            float sr0 = 0.f, sr1 = 0.f, sr2 = 0.f, sr3 = 0.f;
#pragma unroll
            for (int hi = 0; hi < 2; ++hi) {
                float h0 = acc[hi][bj][0]; h0 = h0 > 0.f ? h0 : 0.f;
                float h1 = acc[hi][bj][1]; h1 = h1 > 0.f ? h1 : 0.f;
                float h2 = acc[hi][bj][2]; h2 = h2 > 0.f ? h2 : 0.f;
                float h3 = acc[hi][bj][3]; h3 = h3 > 0.f ? h3 : 0.f;
                sr0 = fmaf(h0, w2v[hi][0], sr0);
                sr1 = fmaf(h1, w2v[hi][1], sr1);
                sr2 = fmaf(h2, w2v[hi][2], sr2);
                sr3 = fmaf(h3, w2v[hi][3], sr3);
            }
            float s = (sr0 + sr1) + (sr2 + sr3);
            // sum the 4 g-groups (hid quarters within this wave's 32 cols)
            s += __shfl_xor(s, 16, 64);
            s += __shfl_xor(s, 32, 64);
            sarr[bj] = s;
        }
        // lane (g*16 + lrow) stores batch row g*16+lrow -> pick bj == g
        float sv = (g == 0) ? sarr[0] : (g == 1) ? sarr[1]
                 : (g == 2) ? sarr[2] : sarr[3];
        partial[cur][w][lane] = sv;

        __syncthreads();   // partial ready; stage(tile+1) drained; Abuf[cur] free
        if (t < 64) {
            float v = ((partial[cur][0][t] + partial[cur][1][t])
                     + (partial[cur][2][t] + partial[cur][3][t]))
                    + ((partial[cur][4][t] + partial[cur][5][t])
                     + (partial[cur][6][t] + partial[cur][7][t]))
                    + b2v + skipv;
            out[(size_t)(r0 + t) * NF + m] = v;
        }
    }
}

// ---------------------------------------------------------------------------
extern "C" void kernel_launch(void* const* d_in, const int* in_sizes, int n_in,
                              void* d_out, int out_size, void* d_ws, size_t ws_size,
                              hipStream_t stream) {
    const float* f_t = (const float*)d_in[0];
    const float* a_t = (const float*)d_in[1];
    const float* W1  = (const float*)d_in[2];
    const float* b1  = (const float*)d_in[3];
    const float* W2  = (const float*)d_in[4];
    const float* b2  = (const float*)d_in[5];
    float* out = (float*)d_out;

    // ws layout: w1t bf16 [128][256][160] (10.49 MB), fab bf16 [4096][192] (1.57 MB)
    __hip_bfloat16* w1t = (__hip_bfloat16*)d_ws;
    __hip_bfloat16* fab = (__hip_bfloat16*)((char*)d_ws + (size_t)NF * HID * KP * 2);

    // converts merged: 1280 w1t blocks + 384 fa blocks
    hipLaunchKernelGGL(convert_all, dim3(1664), dim3(256), 0, stream,
                       W1, b1, f_t, a_t, w1t, fab);
    hipLaunchKernelGGL(fused_mlp, dim3(512), dim3(512), 0, stream,
                       fab, w1t, W2, b2, f_t, out);
}